// Round 1
// baseline (1217.507 us; speedup 1.0000x reference)
//
#include <hip/hip_runtime.h>

#define EDIM 64
#define HDIM 64

__device__ __forceinline__ float fast_sigmoid(float x) {
    // 1 / (1 + 2^(-x*log2e))
    return __builtin_amdgcn_rcpf(1.0f + __builtin_amdgcn_exp2f(-1.4426950408889634f * x));
}
__device__ __forceinline__ float fast_tanh(float x) {
    // 1 - 2/(1 + 2^(2x*log2e))
    return 1.0f - 2.0f * __builtin_amdgcn_rcpf(1.0f + __builtin_amdgcn_exp2f(2.8853900817779268f * x));
}

// One user per 4-wave block (persistent over users, grid-stride).
// wave w = gate w (i,f,g,o); lane l = row within gate; gate row r = w*64+l.
// Lane holds W_ih[r,:] ++ W_hh[r,:] (128 fp32) in VGPRs; [x_t ; h] broadcast from LDS.
__global__ __launch_bounds__(256) void lstm_scatter(
    const int* __restrict__ seq, const int* __restrict__ lens,
    const float* __restrict__ emb,
    const float* __restrict__ W_ih, const float* __restrict__ W_hh,
    const float* __restrict__ b_ih, const float* __restrict__ b_hh,
    float* __restrict__ out_sum, float* __restrict__ cnt,
    int U, int T)
{
    __shared__ __align__(16) float xh[EDIM + HDIM];   // [x_t (64) ; h (64)]
    __shared__ __align__(16) float gl[4 * HDIM];      // gates i,f,g,o

    const int tid = threadIdx.x;
    const int wv  = tid >> 6;        // 0..3 = gate index
    const int l   = tid & 63;        // row within gate = hidden index
    const int r   = (wv << 6) | l;   // gate row 0..255

    // Load this lane's weight row once (persistent block amortizes over ~16 users x ~25 steps).
    float w[128];
    {
        const float4* wi = reinterpret_cast<const float4*>(W_ih + (size_t)r * EDIM);
        const float4* wh = reinterpret_cast<const float4*>(W_hh + (size_t)r * HDIM);
        #pragma unroll
        for (int k = 0; k < 16; ++k) {
            float4 a = wi[k];
            w[4*k+0] = a.x; w[4*k+1] = a.y; w[4*k+2] = a.z; w[4*k+3] = a.w;
        }
        #pragma unroll
        for (int k = 0; k < 16; ++k) {
            float4 a = wh[k];
            w[64+4*k+0] = a.x; w[64+4*k+1] = a.y; w[64+4*k+2] = a.z; w[64+4*k+3] = a.w;
        }
    }
    const float bias = b_ih[r] + b_hh[r];

    for (int u = blockIdx.x; u < U; u += gridDim.x) {
        const int len = lens[u];
        const int* su = seq + (size_t)u * T;
        if (tid < HDIM) xh[EDIM + tid] = 0.0f;   // h0 = 0 (wave 0 only)
        float c = 0.0f;                           // cell state, replicated per wave

        for (int t = 0; t < len; ++t) {
            const int item = su[t];
            if (tid < EDIM) xh[tid] = emb[(size_t)item * EDIM + tid];  // x_t (wave 0)
            __syncthreads();   // barrier A: x_t + h visible

            float acc = bias;
            #pragma unroll
            for (int k = 0; k < 32; ++k) {
                const float4 v = reinterpret_cast<const float4*>(xh)[k];  // ds_read_b128 broadcast
                acc = fmaf(w[4*k+0], v.x, acc);
                acc = fmaf(w[4*k+1], v.y, acc);
                acc = fmaf(w[4*k+2], v.z, acc);
                acc = fmaf(w[4*k+3], v.w, acc);
            }
            gl[r] = (wv == 2) ? fast_tanh(acc) : fast_sigmoid(acc);
            __syncthreads();   // barrier B: gates visible

            const float gi = gl[l];
            const float gf = gl[HDIM + l];
            const float gg = gl[2*HDIM + l];
            const float go = gl[3*HDIM + l];
            c = gf * c + gi * gg;                 // each wave keeps its own replica of c
            const float h = go * fast_tanh(c);

            if (wv == 0) {
                xh[EDIM + l] = h;                 // h for next step (WAR safe: readers passed barrier B)
            } else if (wv == 1) {
                atomicAdd(&out_sum[(size_t)item * HDIM + l], h);   // valid by construction (t < len)
            } else if (wv == 2) {
                if (l == 0) atomicAdd(&cnt[item], 1.0f);
            }
            // next iteration's barrier A separates gl/xh WAR hazards
        }
    }
}

__global__ __launch_bounds__(256) void finalize_mean(
    float* __restrict__ out, const float* __restrict__ cnt, int NI)
{
    const int idx = blockIdx.x * blockDim.x + threadIdx.x;   // one float4 each
    const int total = NI * (HDIM / 4);
    if (idx >= total) return;
    const int i = idx >> 4;                                  // 16 float4 per item row
    const float c = cnt[i];
    const float s = (c > 0.0f) ? __builtin_amdgcn_rcpf(c) : 0.0f;
    float4* o = reinterpret_cast<float4*>(out);
    float4 v = o[idx];
    v.x *= s; v.y *= s; v.z *= s; v.w *= s;
    o[idx] = v;
}

extern "C" void kernel_launch(void* const* d_in, const int* in_sizes, int n_in,
                              void* d_out, int out_size, void* d_ws, size_t ws_size,
                              hipStream_t stream)
{
    const int*   seq  = (const int*)d_in[0];
    const int*   lens = (const int*)d_in[1];
    const float* emb  = (const float*)d_in[2];
    const float* W_ih = (const float*)d_in[3];
    const float* W_hh = (const float*)d_in[4];
    const float* b_ih = (const float*)d_in[5];
    const float* b_hh = (const float*)d_in[6];
    float* out = (float*)d_out;
    float* cnt = (float*)d_ws;   // NI floats of scratch

    const int U  = in_sizes[1];                 // lengths count = num users
    const int T  = in_sizes[0] / U;             // 50
    const int NI = in_sizes[2] / EDIM;          // 100000

    // d_out / d_ws are poisoned 0xAA before every run — zero before accumulating.
    hipMemsetAsync(out, 0, (size_t)NI * HDIM * sizeof(float), stream);
    hipMemsetAsync(cnt, 0, (size_t)NI * sizeof(float), stream);

    lstm_scatter<<<1024, 256, 0, stream>>>(seq, lens, emb, W_ih, W_hh, b_ih, b_hh,
                                           out, cnt, U, T);

    const int total = NI * (HDIM / 4);
    finalize_mean<<<(total + 255) / 256, 256, 0, stream>>>(out, cnt, NI);
}

// Round 2
// 846.708 us; speedup vs baseline: 1.4379x; 1.4379x over previous
//
#include <hip/hip_runtime.h>

#define EDIM 64
#define HDIM 64
#define NSLOT 4
#define PPB 8      // users per block pool (work-stealing within block)

__device__ __forceinline__ float fast_sigmoid(float x) {
    return __builtin_amdgcn_rcpf(1.0f + __builtin_amdgcn_exp2f(-1.4426950408889634f * x));
}
__device__ __forceinline__ float fast_tanh(float x) {
    return 1.0f - 2.0f * __builtin_amdgcn_rcpf(1.0f + __builtin_amdgcn_exp2f(2.8853900817779268f * x));
}

// 4 waves per block; wave wv computes gate wv (rows wv*64+l) for ALL 4 user-slots.
// Wave wv additionally OWNS slot wv: its c-state, h write-back, scatter, refill.
// Weights held in VGPRs (launch_bounds(256,2) gives the allocator room).
__global__ __launch_bounds__(256, 2) void lstm_slots(
    const int* __restrict__ seq, const int* __restrict__ lens,
    const float* __restrict__ emb,
    const float* __restrict__ W_ih, const float* __restrict__ W_hh,
    const float* __restrict__ b_ih, const float* __restrict__ b_hh,
    float* __restrict__ out_sum, float* __restrict__ cnt,
    int U, int T)
{
    __shared__ __align__(16) float xh[NSLOT][EDIM + HDIM]; // per-slot [x_t ; h]
    __shared__ __align__(16) float gl[NSLOT][4][HDIM];     // per-slot gates i,f,g,o
    __shared__ int pool;                                   // next user offset in block range
    __shared__ int actv[NSLOT];

    const int tid = threadIdx.x;
    const int wv  = tid >> 6;        // wave = gate index = owned slot
    const int l   = tid & 63;
    const int r   = (wv << 6) | l;   // gate row 0..255

    // ---- weights into VGPRs (once per block) ----
    float w[128];
    {
        const float4* wi = reinterpret_cast<const float4*>(W_ih + (size_t)r * EDIM);
        const float4* wh = reinterpret_cast<const float4*>(W_hh + (size_t)r * HDIM);
        #pragma unroll
        for (int k = 0; k < 16; ++k) {
            float4 a = wi[k];
            w[4*k+0] = a.x; w[4*k+1] = a.y; w[4*k+2] = a.z; w[4*k+3] = a.w;
        }
        #pragma unroll
        for (int k = 0; k < 16; ++k) {
            float4 a = wh[k];
            w[64+4*k+0] = a.x; w[64+4*k+1] = a.y; w[64+4*k+2] = a.z; w[64+4*k+3] = a.w;
        }
    }
    const float bias = b_ih[r] + b_hh[r];

    const int ubase = blockIdx.x * PPB;
    const int uend  = min(U, ubase + PPB);

    if (tid == 0) pool = 0;
    __syncthreads();

    // ---- initial slot fill: wave wv pops slot wv's first user ----
    int  len = 0, t = 0, item = -1;
    const int* su = nullptr;
    float c = 0.0f;
    bool active = false;
    {
        int p = 0;
        if (l == 0) p = atomicAdd(&pool, 1);
        p = __shfl(p, 0, 64);
        const int u = ubase + p;
        if (u < uend) {
            active = true;
            len = lens[u];
            su  = seq + (size_t)u * T;
            t = 0; c = 0.0f;
            item = su[0];
            xh[wv][l]        = emb[(size_t)item * EDIM + l];  // x_0
            xh[wv][EDIM + l] = 0.0f;                          // h_0
        }
        if (l == 0) actv[wv] = active ? 1 : 0;
    }
    __syncthreads();   // barrier A (iter 0): xh + actv visible

    for (;;) {
        const int a0 = actv[0], a1 = actv[1], a2 = actv[2], a3 = actv[3];
        if (!(a0 | a1 | a2 | a3)) break;

        // prefetch next step's embedding for the owned slot (h-independent)
        float xp = 0.0f; int nit = -1;
        if (active && (t + 1) < len) {
            nit = su[t + 1];
            xp  = emb[(size_t)nit * EDIM + l];   // load issues now, waited in phase 4
        }

        // ---- gate matvecs: for each active slot, 128 FMAs (2 indep chains) ----
        #pragma unroll
        for (int s = 0; s < NSLOT; ++s) {
            const int as = (s == 0) ? a0 : (s == 1) ? a1 : (s == 2) ? a2 : a3;
            if (!as) continue;                       // wave-uniform branch
            const float4* xv = reinterpret_cast<const float4*>(xh[s]);
            float acc0 = bias, acc1 = 0.0f;
            #pragma unroll
            for (int k = 0; k < 32; k += 2) {
                const float4 va = xv[k];
                const float4 vb = xv[k + 1];
                acc0 = fmaf(w[4*k+0], va.x, acc0);
                acc0 = fmaf(w[4*k+1], va.y, acc0);
                acc0 = fmaf(w[4*k+2], va.z, acc0);
                acc0 = fmaf(w[4*k+3], va.w, acc0);
                acc1 = fmaf(w[4*k+4], vb.x, acc1);
                acc1 = fmaf(w[4*k+5], vb.y, acc1);
                acc1 = fmaf(w[4*k+6], vb.z, acc1);
                acc1 = fmaf(w[4*k+7], vb.w, acc1);
            }
            const float g = acc0 + acc1;
            gl[s][wv][l] = (wv == 2) ? fast_tanh(g) : fast_sigmoid(g);
        }
        __syncthreads();   // barrier B: gates visible

        // ---- owned slot: h/c update, scatter, advance/refill ----
        if (active) {
            const float gi = gl[wv][0][l];
            const float gf = gl[wv][1][l];
            const float gg = gl[wv][2][l];
            const float go = gl[wv][3][l];
            c = gf * c + gi * gg;
            const float h = go * fast_tanh(c);

            atomicAdd(&out_sum[(size_t)item * HDIM + l], h);
            if (l == 0) atomicAdd(&cnt[item], 1.0f);

            ++t;
            if (t < len) {
                item = nit;
                xh[wv][EDIM + l] = h;    // h_t for next step
                xh[wv][l]        = xp;   // x_{t+1} (prefetched)
            } else {
                // refill from block pool
                int p = 0;
                if (l == 0) p = atomicAdd(&pool, 1);
                p = __shfl(p, 0, 64);
                const int u = ubase + p;
                if (u < uend) {
                    len = lens[u];
                    su  = seq + (size_t)u * T;
                    t = 0; c = 0.0f;
                    item = su[0];
                    xh[wv][l]        = emb[(size_t)item * EDIM + l];
                    xh[wv][EDIM + l] = 0.0f;
                } else {
                    active = false;
                    if (l == 0) actv[wv] = 0;
                }
            }
        }
        __syncthreads();   // barrier A: xh/actv updates visible for next iter
    }
}

__global__ __launch_bounds__(256) void finalize_mean(
    float* __restrict__ out, const float* __restrict__ cnt, int NI)
{
    const int idx = blockIdx.x * blockDim.x + threadIdx.x;
    const int total = NI * (HDIM / 4);
    if (idx >= total) return;
    const int i = idx >> 4;
    const float c = cnt[i];
    const float s = (c > 0.0f) ? __builtin_amdgcn_rcpf(c) : 0.0f;
    float4* o = reinterpret_cast<float4*>(out);
    float4 v = o[idx];
    v.x *= s; v.y *= s; v.z *= s; v.w *= s;
    o[idx] = v;
}

extern "C" void kernel_launch(void* const* d_in, const int* in_sizes, int n_in,
                              void* d_out, int out_size, void* d_ws, size_t ws_size,
                              hipStream_t stream)
{
    const int*   seq  = (const int*)d_in[0];
    const int*   lens = (const int*)d_in[1];
    const float* emb  = (const float*)d_in[2];
    const float* W_ih = (const float*)d_in[3];
    const float* W_hh = (const float*)d_in[4];
    const float* b_ih = (const float*)d_in[5];
    const float* b_hh = (const float*)d_in[6];
    float* out = (float*)d_out;
    float* cnt = (float*)d_ws;   // NI floats of scratch

    const int U  = in_sizes[1];
    const int T  = in_sizes[0] / U;
    const int NI = in_sizes[2] / EDIM;

    hipMemsetAsync(out, 0, (size_t)NI * HDIM * sizeof(float), stream);
    hipMemsetAsync(cnt, 0, (size_t)NI * sizeof(float), stream);

    const int nblk = (U + PPB - 1) / PPB;
    lstm_slots<<<nblk, 256, 0, stream>>>(seq, lens, emb, W_ih, W_hh, b_ih, b_hh,
                                         out, cnt, U, T);

    const int total = NI * (HDIM / 4);
    finalize_mean<<<(total + 255) / 256, 256, 0, stream>>>(out, cnt, NI);
}

// Round 3
// 550.683 us; speedup vs baseline: 2.2109x; 1.5376x over previous
//
#include <hip/hip_runtime.h>

#define EDIM 64
#define HDIM 64
#define BUSER 16

typedef short bf16x8 __attribute__((ext_vector_type(8)));
typedef float f32x4  __attribute__((ext_vector_type(4)));

__device__ __forceinline__ float fast_sigmoid(float x) {
    return __builtin_amdgcn_rcpf(1.0f + __builtin_amdgcn_exp2f(-1.4426950408889634f * x));
}
__device__ __forceinline__ float fast_tanh(float x) {
    return 1.0f - 2.0f * __builtin_amdgcn_rcpf(1.0f + __builtin_amdgcn_exp2f(2.8853900817779268f * x));
}
__device__ __forceinline__ unsigned short f2bf(float f) {   // RNE truncation
    unsigned int u = __float_as_uint(f);
    return (unsigned short)((u + 0x7FFF + ((u >> 16) & 1)) >> 16);
}
__device__ __forceinline__ unsigned int pack2bf(float a, float b) {
    return (unsigned int)f2bf(a) | ((unsigned int)f2bf(b) << 16);
}
// LDS-only barrier: waits ds ops, leaves global loads (prefetch) in flight.
__device__ __forceinline__ void barrier_lds() {
    asm volatile("s_waitcnt lgkmcnt(0)" ::: "memory");
    __builtin_amdgcn_s_barrier();
}
__device__ __forceinline__ int swz(int user, int byteoff) {
    return byteoff ^ ((user & 7) << 4);
}

// ---------- counting sort by length (group equal lengths into blocks) ----------
__global__ void k_hist(const int* __restrict__ lens, int U, int* __restrict__ hist) {
    int u = blockIdx.x * 256 + threadIdx.x;
    if (u < U) atomicAdd(&hist[lens[u]], 1);
}
__global__ void k_scan(const int* __restrict__ hist, int* __restrict__ off) {
    if (threadIdx.x == 0) { int s = 0; for (int l = 0; l <= 50; ++l) { off[l] = s; s += hist[l]; } }
}
__global__ void k_place(const int* __restrict__ lens, int U, int* __restrict__ off, int* __restrict__ order) {
    int u = blockIdx.x * 256 + threadIdx.x;
    if (u < U) { int p = atomicAdd(&off[lens[u]], 1); order[p] = u; }
}

// ---------- batched LSTM: 16 users/block, MFMA gates ----------
__global__ __launch_bounds__(256) void lstm_batch(
    const int* __restrict__ seq, const int* __restrict__ lens,
    const float* __restrict__ emb,
    const float* __restrict__ W_ih, const float* __restrict__ W_hh,
    const float* __restrict__ b_ih, const float* __restrict__ b_hh,
    const int* __restrict__ order,
    float* __restrict__ out_sum, float* __restrict__ cnt,
    int U, int T)
{
    __shared__ __align__(16) unsigned char xh[BUSER * 256];  // [user][128 bf16], XOR-swizzled
    __shared__ int marr[BUSER];

    const int tid  = threadIdx.x;
    const int wv   = tid >> 6;
    const int lane = tid & 63;
    const int base = blockIdx.x * BUSER;

    // roles: gather user gu = tid>>4 (quad kq = tid&15); compute/scatter user su = lane&15
    const int gu = tid >> 4, kq = tid & 15;
    const int su = lane & 15, kh = (lane >> 4) & 3;   // kh = lane>>4 group

    int ug = -1, us = -1;
    if (base + gu < U) ug = order[base + gu];
    if (base + su < U) us = order[base + su];
    const int len_g = (ug >= 0) ? lens[ug] : 0;
    const int len_s = (us >= 0) ? lens[us] : 0;
    const int* seqg = seq + (size_t)(ug < 0 ? 0 : ug) * T;
    const int* seqs = seq + (size_t)(us < 0 ? 0 : us) * T;

    if (tid < BUSER) marr[tid] = len_s;   // tid<16 -> su==tid
    __syncthreads();
    int mT = 0;
    #pragma unroll
    for (int s = 0; s < BUSER; ++s) mT = max(mT, marr[s]);

    // ---- weight fragments: wfrag[gate j][ktile], A[16x32] per MFMA ----
    bf16x8 wfrag[4][4];
    #pragma unroll
    for (int j = 0; j < 4; ++j) {
        const int row = j * 64 + wv * 16 + su;        // su == lane&15 == A row-in-tile
        #pragma unroll
        for (int kt = 0; kt < 4; ++kt) {
            const float* src = (kt < 2)
                ? (W_ih + (size_t)row * EDIM + kt * 32 + kh * 8)
                : (W_hh + (size_t)row * HDIM + (kt - 2) * 32 + kh * 8);
            float4 a = *reinterpret_cast<const float4*>(src);
            float4 b = *reinterpret_cast<const float4*>(src + 4);
            bf16x8 w;
            w[0] = (short)f2bf(a.x); w[1] = (short)f2bf(a.y);
            w[2] = (short)f2bf(a.z); w[3] = (short)f2bf(a.w);
            w[4] = (short)f2bf(b.x); w[5] = (short)f2bf(b.y);
            w[6] = (short)f2bf(b.z); w[7] = (short)f2bf(b.w);
            wfrag[j][kt] = w;
        }
    }
    float bias_[4][4];
    #pragma unroll
    for (int j = 0; j < 4; ++j)
        #pragma unroll
        for (int r = 0; r < 4; ++r) {
            const int gi = j * 64 + wv * 16 + kh * 4 + r;
            bias_[j][r] = b_ih[gi] + b_hh[gi];
        }

    // zero h-region of xh
    {
        unsigned int* p = reinterpret_cast<unsigned int*>(&xh[swz(gu, gu * 256 + 128 + kq * 8)]);
        p[0] = 0u; p[1] = 0u;
    }

    float c[4] = {0.f, 0.f, 0.f, 0.f}, h[4];
    const float4* emb4 = reinterpret_cast<const float4*>(emb);

    // prefetch step 0 embedding
    int itcur = -1; float4 xcur;
    if (0 < len_g) { itcur = seqg[0]; xcur = emb4[(size_t)itcur * 16 + kq]; }

    for (int t = 0; t < mT; ++t) {
        barrier_lds();   // prev-iter xh reads + marr/h0 done
        // commit x_t (prefetched) and h_{t} (from prev iter regs)
        if (itcur >= 0) {
            unsigned int* p = reinterpret_cast<unsigned int*>(&xh[swz(gu, gu * 256 + kq * 8)]);
            p[0] = pack2bf(xcur.x, xcur.y);
            p[1] = pack2bf(xcur.z, xcur.w);
            if (kq == 0) atomicAdd(&cnt[itcur], 1.0f);
        }
        if (t > 0) {
            unsigned int* p = reinterpret_cast<unsigned int*>(&xh[swz(su, su * 256 + 128 + wv * 32 + kh * 8)]);
            p[0] = pack2bf(h[0], h[1]);
            p[1] = pack2bf(h[2], h[3]);
        }
        // prefetch t+1 (h-independent)
        int itn = -1; float4 xn;
        if (t + 1 < len_g) { itn = seqg[t + 1]; xn = emb4[(size_t)itn * 16 + kq]; }

        barrier_lds();   // xh ready

        f32x4 acc[4] = {{0,0,0,0},{0,0,0,0},{0,0,0,0},{0,0,0,0}};
        #pragma unroll
        for (int kt = 0; kt < 4; ++kt) {
            uint4 braw = *reinterpret_cast<const uint4*>(&xh[swz(su, su * 256 + kt * 64 + kh * 16)]);
            bf16x8 bf = __builtin_bit_cast(bf16x8, braw);
            acc[0] = __builtin_amdgcn_mfma_f32_16x16x32_bf16(wfrag[0][kt], bf, acc[0], 0, 0, 0);
            acc[1] = __builtin_amdgcn_mfma_f32_16x16x32_bf16(wfrag[1][kt], bf, acc[1], 0, 0, 0);
            acc[2] = __builtin_amdgcn_mfma_f32_16x16x32_bf16(wfrag[2][kt], bf, acc[2], 0, 0, 0);
            acc[3] = __builtin_amdgcn_mfma_f32_16x16x32_bf16(wfrag[3][kt], bf, acc[3], 0, 0, 0);
        }
        // nonlinearity + state update (fp32): lane holds (user su, hu = wv*16+kh*4+r)
        #pragma unroll
        for (int r = 0; r < 4; ++r) {
            const float gi = fast_sigmoid(acc[0][r] + bias_[0][r]);
            const float gf = fast_sigmoid(acc[1][r] + bias_[1][r]);
            const float gg = fast_tanh   (acc[2][r] + bias_[2][r]);
            const float go = fast_sigmoid(acc[3][r] + bias_[3][r]);
            c[r] = gf * c[r] + gi * gg;
            h[r] = go * fast_tanh(c[r]);
        }
        // scatter h for valid steps
        const int its = (t < len_s) ? seqs[t] : -1;
        if (its >= 0) {
            float* o = out_sum + (size_t)its * HDIM + wv * 16 + kh * 4;
            atomicAdd(o + 0, h[0]); atomicAdd(o + 1, h[1]);
            atomicAdd(o + 2, h[2]); atomicAdd(o + 3, h[3]);
        }
        itcur = itn; xcur = xn;
    }
}

__global__ __launch_bounds__(256) void finalize_mean(
    float* __restrict__ out, const float* __restrict__ cnt, int NI)
{
    const int idx = blockIdx.x * blockDim.x + threadIdx.x;
    const int total = NI * (HDIM / 4);
    if (idx >= total) return;
    const int i = idx >> 4;
    const float c = cnt[i];
    const float s = (c > 0.0f) ? __builtin_amdgcn_rcpf(c) : 0.0f;
    float4* o = reinterpret_cast<float4*>(out);
    float4 v = o[idx];
    v.x *= s; v.y *= s; v.z *= s; v.w *= s;
    o[idx] = v;
}

extern "C" void kernel_launch(void* const* d_in, const int* in_sizes, int n_in,
                              void* d_out, int out_size, void* d_ws, size_t ws_size,
                              hipStream_t stream)
{
    const int*   seq  = (const int*)d_in[0];
    const int*   lens = (const int*)d_in[1];
    const float* emb  = (const float*)d_in[2];
    const float* W_ih = (const float*)d_in[3];
    const float* W_hh = (const float*)d_in[4];
    const float* b_ih = (const float*)d_in[5];
    const float* b_hh = (const float*)d_in[6];
    float* out = (float*)d_out;

    const int U  = in_sizes[1];
    const int T  = in_sizes[0] / U;
    const int NI = in_sizes[2] / EDIM;

    // workspace layout: cnt[NI] f32 | hist[64] i32 | off[64] i32 | order[U] i32
    float* cnt  = (float*)d_ws;
    int*   hist = (int*)d_ws + NI;
    int*   off  = hist + 64;
    int*   order= off + 64;

    hipMemsetAsync(out, 0, (size_t)NI * HDIM * sizeof(float), stream);
    hipMemsetAsync(d_ws, 0, ((size_t)NI + 128) * sizeof(float), stream);

    const int ublk = (U + 255) / 256;
    k_hist <<<ublk, 256, 0, stream>>>(lens, U, hist);
    k_scan <<<1, 64, 0, stream>>>(hist, off);
    k_place<<<ublk, 256, 0, stream>>>(lens, U, off, order);

    const int nblk = (U + BUSER - 1) / BUSER;
    lstm_batch<<<nblk, 256, 0, stream>>>(seq, lens, emb, W_ih, W_hh, b_ih, b_hh,
                                         order, out, cnt, U, T);

    const int total = NI * (HDIM / 4);
    finalize_mean<<<(total + 255) / 256, 256, 0, stream>>>(out, cnt, NI);
}

// Round 4
// 306.500 us; speedup vs baseline: 3.9723x; 1.7967x over previous
//
#include <hip/hip_runtime.h>

#define EDIM 64
#define HDIM 64

typedef short bf16x8 __attribute__((ext_vector_type(8)));
typedef float f32x4  __attribute__((ext_vector_type(4)));

__device__ __forceinline__ float fast_sigmoid(float x) {
    return __builtin_amdgcn_rcpf(1.0f + __builtin_amdgcn_exp2f(-1.4426950408889634f * x));
}
__device__ __forceinline__ float fast_tanh(float x) {
    return 1.0f - 2.0f * __builtin_amdgcn_rcpf(1.0f + __builtin_amdgcn_exp2f(2.8853900817779268f * x));
}
__device__ __forceinline__ unsigned short f2bf(float f) {   // RNE
    unsigned int u = __float_as_uint(f);
    return (unsigned short)((u + 0x7FFF + ((u >> 16) & 1)) >> 16);
}
__device__ __forceinline__ bf16x8 pack8(float4 a, float4 b) {
    bf16x8 w;
    w[0]=(short)f2bf(a.x); w[1]=(short)f2bf(a.y); w[2]=(short)f2bf(a.z); w[3]=(short)f2bf(a.w);
    w[4]=(short)f2bf(b.x); w[5]=(short)f2bf(b.y); w[6]=(short)f2bf(b.z); w[7]=(short)f2bf(b.w);
    return w;
}
// hidden-unit permutation: lane(su,q) reg (hb,r) owns hu(hb,q,r); chosen so that
// the next step's B-fragment (lane q needs h[q*8+j] / h[32+q*8+j]) is lane-local.
__device__ __forceinline__ int hu_of(int hb, int q, int r) {
    return ((hb >> 1) << 5) + (q << 3) + ((hb & 1) << 2) + r;
}

// ---------- counting sort by length, DESCENDING (LPT schedule) ----------
__global__ void k_hist(const int* __restrict__ lens, int U, int* __restrict__ hist) {
    int u = blockIdx.x * 256 + threadIdx.x;
    if (u < U) atomicAdd(&hist[lens[u]], 1);
}
__global__ void k_scan(const int* __restrict__ hist, int* __restrict__ off) {
    if (threadIdx.x == 0) { int s = 0; for (int l = 50; l >= 1; --l) { off[l] = s; s += hist[l]; } off[0] = s; }
}
__global__ void k_place(const int* __restrict__ lens, int U, int* __restrict__ off, int* __restrict__ order) {
    int u = blockIdx.x * 256 + threadIdx.x;
    if (u < U) { int p = atomicAdd(&off[lens[u]], 1); order[p] = u; }
}

// ---------- barrier-free LSTM: one independent 16-user batch per wave ----------
__global__ __launch_bounds__(256, 1) void lstm_wave(
    const int* __restrict__ seq, const int* __restrict__ lens,
    const float* __restrict__ emb,
    const float* __restrict__ W_ih, const float* __restrict__ W_hh,
    const float* __restrict__ b_ih, const float* __restrict__ b_hh,
    const int* __restrict__ order,
    float* __restrict__ out_sum, float* __restrict__ cnt,
    int U, int T)
{
    // LDS: [0,32K) = W_ih fragment array (16 rt x 2 kt x 64 lanes x 16B); [32K,48K) = per-wave h transpose
    __shared__ __align__(16) unsigned char lds[32768 + 4 * 4096];
    const int tid  = threadIdx.x;
    const int wv   = tid >> 6;
    const int lane = tid & 63;
    const int su   = lane & 15;     // B/D column = user slot
    const int q    = lane >> 4;     // k-group / D-row group

    // ---- stage W_ih (x-path, kt=0,1) as a contiguous fragment array ----
    for (int s = tid; s < 2048; s += 256) {
        const int rt = s >> 7, kt = (s >> 6) & 1, l = s & 63;
        const int g = rt >> 2, hb = rt & 3;
        const int rho = l & 15, qf = l >> 4;
        const int grow = g * 64 + hu_of(hb, rho >> 2, rho & 3);
        const float* src = W_ih + (size_t)grow * EDIM + kt * 32 + qf * 8;
        float4 a = *reinterpret_cast<const float4*>(src);
        float4 b = *reinterpret_cast<const float4*>(src + 4);
        *reinterpret_cast<bf16x8*>(lds + (size_t)s * 16) = pack8(a, b);
    }

    // ---- W_hh (h-path, kt=2,3) fragments permanently in VGPRs (128 regs) ----
    bf16x8 whreg[4][4][2];
    {
        const int rho = lane & 15, qf = lane >> 4;
        #pragma unroll
        for (int g = 0; g < 4; ++g)
            #pragma unroll
            for (int hb = 0; hb < 4; ++hb) {
                const int grow = g * 64 + hu_of(hb, rho >> 2, rho & 3);
                const float* src = W_hh + (size_t)grow * HDIM + qf * 8;
                #pragma unroll
                for (int kp = 0; kp < 2; ++kp) {
                    float4 a = *reinterpret_cast<const float4*>(src + kp * 32);
                    float4 b = *reinterpret_cast<const float4*>(src + kp * 32 + 4);
                    whreg[g][hb][kp] = pack8(a, b);
                }
            }
    }
    // ---- per-lane bias vectors (fp32) ----
    f32x4 biasv[4][4];
    #pragma unroll
    for (int g = 0; g < 4; ++g)
        #pragma unroll
        for (int hb = 0; hb < 4; ++hb)
            #pragma unroll
            for (int r = 0; r < 4; ++r) {
                const int grow = g * 64 + hu_of(hb, q, r);
                biasv[g][hb][r] = b_ih[grow] + b_hh[grow];
            }

    __syncthreads();   // the ONLY block barrier: W_ih staging visible

    // ---- user assignment: rank-interleaved so each CU gets a length mix ----
    const int nblk = gridDim.x;
    const int wbase = (wv * nblk + blockIdx.x) * 16;
    int us = 0, len = 0;
    if (wbase + su < U) { us = order[wbase + su]; len = lens[us]; }
    const int* sp = seq + (size_t)us * T;
    const int mT = __shfl(len, 0, 64);      // rank wbase is the longest in this wave
    if (mT == 0) return;

    // ---- software pipeline: item(t), item(t+1) and x(t) pre-loaded ----
    const float4* e4 = reinterpret_cast<const float4*>(emb);
    int itc = sp[0];
    int itn = (mT > 1) ? sp[1] : itc;
    bf16x8 bx0, bx1, bh0 = {0,0,0,0,0,0,0,0}, bh1 = {0,0,0,0,0,0,0,0};
    {
        const size_t eb = (size_t)itc * 16 + q * 2;
        float4 xa = e4[eb], xb = e4[eb + 1], xc = e4[eb + 8], xd = e4[eb + 9];
        bx0 = pack8(xa, xb); bx1 = pack8(xc, xd);
    }
    f32x4 cst[4] = {{0,0,0,0},{0,0,0,0},{0,0,0,0},{0,0,0,0}};
    const int XP = 32768 + wv * 4096;

    for (int t = 0; t < mT; ++t) {
        // prefetch x(t+1) and item(t+2) — h-independent, retire under compute
        float4 na, nb, nc, nd; int sn = itn;
        const bool pf = (t + 1 < mT);
        if (pf) {
            const size_t eb = (size_t)itn * 16 + q * 2;
            na = e4[eb]; nb = e4[eb + 1]; nc = e4[eb + 8]; nd = e4[eb + 9];
        }
        if (t + 2 < mT) sn = sp[t + 2];

        f32x4 hn[4];
        #pragma unroll
        for (int hb = 0; hb < 4; ++hb) {
            bf16x8 wx0[4], wx1[4];
            #pragma unroll
            for (int g = 0; g < 4; ++g) {
                const int rt = g * 4 + hb;
                wx0[g] = *reinterpret_cast<const bf16x8*>(lds + ((rt * 2 + 0) * 64 + lane) * 16);
                wx1[g] = *reinterpret_cast<const bf16x8*>(lds + ((rt * 2 + 1) * 64 + lane) * 16);
            }
            f32x4 acc[4];
            #pragma unroll
            for (int g = 0; g < 4; ++g) {
                acc[g] = biasv[g][hb];
                acc[g] = __builtin_amdgcn_mfma_f32_16x16x32_bf16(wx0[g], bx0, acc[g], 0, 0, 0);
                acc[g] = __builtin_amdgcn_mfma_f32_16x16x32_bf16(wx1[g], bx1, acc[g], 0, 0, 0);
                acc[g] = __builtin_amdgcn_mfma_f32_16x16x32_bf16(whreg[g][hb][0], bh0, acc[g], 0, 0, 0);
                acc[g] = __builtin_amdgcn_mfma_f32_16x16x32_bf16(whreg[g][hb][1], bh1, acc[g], 0, 0, 0);
            }
            #pragma unroll
            for (int r = 0; r < 4; ++r) {
                const float gi = fast_sigmoid(acc[0][r]);
                const float gf = fast_sigmoid(acc[1][r]);
                const float gg = fast_tanh   (acc[2][r]);
                const float go = fast_sigmoid(acc[3][r]);
                const float cc = gf * cst[hb][r] + gi * gg;
                cst[hb][r] = cc;
                hn[hb][r] = go * fast_tanh(cc);
            }
        }
        // next-step h B-fragments: purely lane-local thanks to hu permutation
        bh0[0]=(short)f2bf(hn[0][0]); bh0[1]=(short)f2bf(hn[0][1]); bh0[2]=(short)f2bf(hn[0][2]); bh0[3]=(short)f2bf(hn[0][3]);
        bh0[4]=(short)f2bf(hn[1][0]); bh0[5]=(short)f2bf(hn[1][1]); bh0[6]=(short)f2bf(hn[1][2]); bh0[7]=(short)f2bf(hn[1][3]);
        bh1[0]=(short)f2bf(hn[2][0]); bh1[1]=(short)f2bf(hn[2][1]); bh1[2]=(short)f2bf(hn[2][2]); bh1[3]=(short)f2bf(hn[2][3]);
        bh1[4]=(short)f2bf(hn[3][0]); bh1[5]=(short)f2bf(hn[3][1]); bh1[6]=(short)f2bf(hn[3][2]); bh1[7]=(short)f2bf(hn[3][3]);

        // ---- scatter: per-wave LDS transpose -> dense per-item 64-dword atomics ----
        const bool val = (t < len);
        #pragma unroll
        for (int hb = 0; hb < 4; ++hb) {
            f32x4 w4;
            #pragma unroll
            for (int r = 0; r < 4; ++r) w4[r] = val ? hn[hb][r] : 0.0f;
            int byte = (su * 64 + hu_of(hb, q, 0)) * 4;
            byte ^= (su & 7) << 4;                       // bank swizzle
            *reinterpret_cast<f32x4*>(lds + XP + byte) = w4;
        }
        asm volatile("s_waitcnt lgkmcnt(0)" ::: "memory");
        #pragma unroll
        for (int g = 0; g < 16; ++g) {
            const int itg = __shfl(itc, g, 64);          // item of user-slot g (lane g holds it)
            int byte = (g * 64 + lane) * 4;
            byte ^= (g & 7) << 4;
            const float hv = *reinterpret_cast<const float*>(lds + XP + byte);
            atomicAdd(&out_sum[(size_t)itg * HDIM + lane], hv);   // 64 consecutive dwords
        }
        if (q == 0 && val) atomicAdd(&cnt[itc], 1.0f);

        // rotate pipeline
        if (pf) { bx0 = pack8(na, nb); bx1 = pack8(nc, nd); itc = itn; itn = sn; }
    }
}

__global__ __launch_bounds__(256) void finalize_mean(
    float* __restrict__ out, const float* __restrict__ cnt, int NI)
{
    const int idx = blockIdx.x * blockDim.x + threadIdx.x;
    const int total = NI * (HDIM / 4);
    if (idx >= total) return;
    const int i = idx >> 4;
    const float c = cnt[i];
    const float s = (c > 0.0f) ? __builtin_amdgcn_rcpf(c) : 0.0f;
    float4* o = reinterpret_cast<float4*>(out);
    float4 v = o[idx];
    v.x *= s; v.y *= s; v.z *= s; v.w *= s;
    o[idx] = v;
}

extern "C" void kernel_launch(void* const* d_in, const int* in_sizes, int n_in,
                              void* d_out, int out_size, void* d_ws, size_t ws_size,
                              hipStream_t stream)
{
    const int*   seq  = (const int*)d_in[0];
    const int*   lens = (const int*)d_in[1];
    const float* emb  = (const float*)d_in[2];
    const float* W_ih = (const float*)d_in[3];
    const float* W_hh = (const float*)d_in[4];
    const float* b_ih = (const float*)d_in[5];
    const float* b_hh = (const float*)d_in[6];
    float* out = (float*)d_out;

    const int U  = in_sizes[1];
    const int T  = in_sizes[0] / U;
    const int NI = in_sizes[2] / EDIM;

    // ws layout: cnt[NI] f32 | hist[64] i32 | off[64] i32 | order[U] i32
    float* cnt   = (float*)d_ws;
    int*   hist  = (int*)d_ws + NI;
    int*   off   = hist + 64;
    int*   order = off + 64;

    hipMemsetAsync(out, 0, (size_t)NI * HDIM * sizeof(float), stream);
    hipMemsetAsync(d_ws, 0, ((size_t)NI + 128) * sizeof(float), stream);

    const int ublk = (U + 255) / 256;
    k_hist <<<ublk, 256, 0, stream>>>(lens, U, hist);
    k_scan <<<1, 64, 0, stream>>>(hist, off);
    k_place<<<ublk, 256, 0, stream>>>(lens, U, off, order);

    const int nblk = (U + 63) / 64;   // 64 users per block (4 independent waves x 16)
    lstm_wave<<<nblk, 256, 0, stream>>>(seq, lens, emb, W_ih, W_hh, b_ih, b_hh,
                                        order, out, cnt, U, T);

    const int total = NI * (HDIM / 4);
    finalize_mean<<<(total + 255) / 256, 256, 0, stream>>>(out, cnt, NI);
}

// Round 6
// 299.381 us; speedup vs baseline: 4.0667x; 1.0238x over previous
//
#include <hip/hip_runtime.h>

#define EDIM 64
#define HDIM 64
#define S_SIG  (-1.4426950408889634f)
#define S_TANH ( 2.8853900817779268f)

typedef short bf16x8 __attribute__((ext_vector_type(8)));
typedef float f32x4  __attribute__((ext_vector_type(4)));

__device__ __forceinline__ float rcp_(float x){ return __builtin_amdgcn_rcpf(x); }
__device__ __forceinline__ float exp2_(float x){ return __builtin_amdgcn_exp2f(x); }
__device__ __forceinline__ unsigned short f2bf(float f) {   // RNE
    unsigned int u = __float_as_uint(f);
    return (unsigned short)((u + 0x7FFF + ((u >> 16) & 1)) >> 16);
}
__device__ __forceinline__ bf16x8 pack8s(float4 a, float4 b, float s) {
    bf16x8 w;
    w[0]=(short)f2bf(a.x*s); w[1]=(short)f2bf(a.y*s); w[2]=(short)f2bf(a.z*s); w[3]=(short)f2bf(a.w*s);
    w[4]=(short)f2bf(b.x*s); w[5]=(short)f2bf(b.y*s); w[6]=(short)f2bf(b.z*s); w[7]=(short)f2bf(b.w*s);
    return w;
}
__device__ __forceinline__ unsigned int cvtpk(float lo, float hi) {
    unsigned int r;
    asm("v_cvt_pk_bf16_f32 %0, %1, %2" : "=v"(r) : "v"(lo), "v"(hi));
    return r;
}
// hidden-unit permutation: D-reg (hb,q,r) owns hu; next-step B-fragment is lane-local.
__device__ __forceinline__ int hu_of(int hb, int q, int r) {
    return ((hb >> 1) << 5) + (q << 3) + ((hb & 1) << 2) + r;
}

// ---------- fused counting sort (desc length), one block, LDS hist ----------
__global__ __launch_bounds__(1024) void k_sort(const int* __restrict__ lens, int U,
                                               int* __restrict__ order) {
    __shared__ int hist[52];
    __shared__ int base[52];
    const int tid = threadIdx.x;
    if (tid < 52) hist[tid] = 0;
    __syncthreads();
    for (int u = tid; u < U; u += 1024) atomicAdd(&hist[lens[u]], 1);
    __syncthreads();
    if (tid == 0) { int s = 0; for (int l = 50; l >= 0; --l) { base[l] = s; s += hist[l]; } }
    __syncthreads();
    for (int u = tid; u < U; u += 1024) { int p = atomicAdd(&base[lens[u]], 1); order[p] = u; }
}

// ---------- barrier-free LSTM: one independent 16-user batch per wave ----------
__global__ __launch_bounds__(256, 1) void lstm_wave(
    const int* __restrict__ seq, const int* __restrict__ lens,
    const float* __restrict__ emb,
    const float* __restrict__ W_ih, const float* __restrict__ W_hh,
    const float* __restrict__ b_ih, const float* __restrict__ b_hh,
    const int* __restrict__ order,
    float* __restrict__ out_sum, float* __restrict__ cnt,
    int U, int T)
{
    __shared__ __align__(16) unsigned char lds[4 * 4096];   // per-wave scatter transpose
    const int tid  = threadIdx.x;
    const int wv   = tid >> 6;
    const int lane = tid & 63;
    const int su   = lane & 15;     // B/D column = user slot; also A-row within tile
    const int q    = lane >> 4;     // k-group / D-row group

    // ---- all weights in registers, pre-scaled by the exp2 gate constants ----
    bf16x8 wx[4][4][2], wh[4][4][2];
    f32x4  biasv[4][4];
    #pragma unroll
    for (int g = 0; g < 4; ++g) {
        const float s = (g == 2) ? S_TANH : S_SIG;
        #pragma unroll
        for (int hb = 0; hb < 4; ++hb) {
            const int grow = g * 64 + hu_of(hb, su >> 2, su & 3);
            const float* wi = W_ih + (size_t)grow * EDIM + q * 8;
            const float* wp = W_hh + (size_t)grow * HDIM + q * 8;
            #pragma unroll
            for (int kp = 0; kp < 2; ++kp) {
                float4 a = *reinterpret_cast<const float4*>(wi + kp * 32);
                float4 b = *reinterpret_cast<const float4*>(wi + kp * 32 + 4);
                wx[g][hb][kp] = pack8s(a, b, s);
                float4 c2 = *reinterpret_cast<const float4*>(wp + kp * 32);
                float4 d2 = *reinterpret_cast<const float4*>(wp + kp * 32 + 4);
                wh[g][hb][kp] = pack8s(c2, d2, s);
            }
            #pragma unroll
            for (int r = 0; r < 4; ++r) {
                const int gi2 = g * 64 + hu_of(hb, q, r);
                biasv[g][hb][r] = s * (b_ih[gi2] + b_hh[gi2]);
            }
        }
    }

    // ---- serpentine wave->user-group assignment (sum-balanced per block) ----
    const int nblk = gridDim.x;
    const int grp  = (wv & 1) ? ((wv + 1) * nblk - 1 - blockIdx.x)
                              : (wv * nblk + blockIdx.x);
    const int wbase = grp * 16;
    int us = 0, len = 0;
    if (wbase + su < U) { us = order[wbase + su]; len = lens[us]; }
    const int* sp = seq + (size_t)us * T;
    int mT = len;
    mT = max(mT, __shfl_xor(mT, 1, 64));
    mT = max(mT, __shfl_xor(mT, 2, 64));
    mT = max(mT, __shfl_xor(mT, 4, 64));
    mT = max(mT, __shfl_xor(mT, 8, 64));
    if (mT <= 0) return;

    const float4* e4 = reinterpret_cast<const float4*>(emb);
    int itc = sp[0];
    int itn = (1 < mT) ? sp[1] : itc;
    bf16x8 bx0, bx1, bh0 = {0,0,0,0,0,0,0,0}, bh1 = {0,0,0,0,0,0,0,0};
    {
        const size_t eb = (size_t)itc * 16 + q * 2;
        bx0 = pack8s(e4[eb],     e4[eb + 1], 1.0f);
        bx1 = pack8s(e4[eb + 8], e4[eb + 9], 1.0f);
    }
    f32x4 cst[4] = {{0,0,0,0},{0,0,0,0},{0,0,0,0},{0,0,0,0}};
    f32x4 hs[4];              // masked h payload pending scatter (prev step)
    int   itp = 0, vprev = 0; // prev item / valid (per-lane, user su)
    const int XP = wv * 4096;

    auto scatter_prev = [&]() {
        #pragma unroll
        for (int hb = 0; hb < 4; ++hb) {
            int byte = (su * 64 + hu_of(hb, q, 0)) * 4;
            byte ^= (su & 7) << 4;                     // bank swizzle
            *reinterpret_cast<f32x4*>(lds + XP + byte) = hs[hb];
        }
        asm volatile("s_waitcnt lgkmcnt(0)" ::: "memory");
        #pragma unroll
        for (int g = 0; g < 16; ++g) {
            const int itg = __builtin_amdgcn_readlane(itp, g);   // wave-uniform item
            const int byte = ((g * 64 + lane) * 4) ^ ((g & 7) << 4);
            const float hv = *reinterpret_cast<const float*>(lds + XP + byte);
            atomicAdd(&out_sum[(size_t)itg * HDIM + lane], hv);  // 64 consecutive dwords
        }
        if (q == 0 && vprev) atomicAdd(&cnt[itp], 1.0f);
    };

    for (int t = 0; t < mT; ++t) {
        // ---- prefetch x(t+1), item(t+2) (h-independent) ----
        float4 na, nb, nc, nd; int sn = itn;
        const bool pf = (t + 1 < mT);
        if (pf) {
            const size_t eb = (size_t)itn * 16 + q * 2;
            na = e4[eb]; nb = e4[eb + 1]; nc = e4[eb + 8]; nd = e4[eb + 9];
        }
        if (t + 2 < mT) sn = sp[t + 2];

        // ---- scatter previous step (fire-and-forget atomics) ----
        if (t > 0) scatter_prev();

        // ---- MFMA gates + nonlinearity, per hb row-block ----
        f32x4 hn[4];
        #pragma unroll
        for (int hb = 0; hb < 4; ++hb) {
            f32x4 acc[4];
            #pragma unroll
            for (int g = 0; g < 4; ++g) {
                acc[g] = biasv[g][hb];
                acc[g] = __builtin_amdgcn_mfma_f32_16x16x32_bf16(wx[g][hb][0], bx0, acc[g], 0, 0, 0);
                acc[g] = __builtin_amdgcn_mfma_f32_16x16x32_bf16(wx[g][hb][1], bx1, acc[g], 0, 0, 0);
                acc[g] = __builtin_amdgcn_mfma_f32_16x16x32_bf16(wh[g][hb][0], bh0, acc[g], 0, 0, 0);
                acc[g] = __builtin_amdgcn_mfma_f32_16x16x32_bf16(wh[g][hb][1], bh1, acc[g], 0, 0, 0);
            }
            #pragma unroll
            for (int r = 0; r < 4; ++r) {           // pre-acts already exp2-scaled
                const float ei = exp2_(acc[0][r]);
                const float ef = exp2_(acc[1][r]);
                const float eg = exp2_(acc[2][r]);
                const float eo = exp2_(acc[3][r]);
                const float gi = rcp_(1.0f + ei);
                const float gf = rcp_(1.0f + ef);
                const float gg = 1.0f - 2.0f * rcp_(1.0f + eg);
                const float go = rcp_(1.0f + eo);
                const float cc = gf * cst[hb][r] + gi * gg;
                cst[hb][r] = cc;
                const float et = exp2_(S_TANH * cc);
                const float th = 1.0f - 2.0f * rcp_(1.0f + et);
                hn[hb][r] = go * th;
            }
        }
        // ---- pack next-step h B-fragments (lane-local via hu permutation) ----
        uint4 p0, p1;
        p0.x = cvtpk(hn[0][0], hn[0][1]); p0.y = cvtpk(hn[0][2], hn[0][3]);
        p0.z = cvtpk(hn[1][0], hn[1][1]); p0.w = cvtpk(hn[1][2], hn[1][3]);
        p1.x = cvtpk(hn[2][0], hn[2][1]); p1.y = cvtpk(hn[2][2], hn[2][3]);
        p1.z = cvtpk(hn[3][0], hn[3][1]); p1.w = cvtpk(hn[3][2], hn[3][3]);
        bh0 = __builtin_bit_cast(bf16x8, p0);
        bh1 = __builtin_bit_cast(bf16x8, p1);

        // ---- save scatter state (mask invalid steps to 0) ----
        const int val = (t < len) ? 1 : 0;
        const float vm = val ? 1.0f : 0.0f;
        #pragma unroll
        for (int hb = 0; hb < 4; ++hb)
            #pragma unroll
            for (int r = 0; r < 4; ++r) hs[hb][r] = hn[hb][r] * vm;
        itp = itc; vprev = val;

        // ---- rotate pipeline ----
        if (pf) { bx0 = pack8s(na, nb, 1.0f); bx1 = pack8s(nc, nd, 1.0f); itc = itn; itn = sn; }
    }
    scatter_prev();   // epilogue: last step's h
}

__global__ __launch_bounds__(256) void finalize_mean(
    float* __restrict__ out, const float* __restrict__ cnt, int NI)
{
    const int idx = blockIdx.x * blockDim.x + threadIdx.x;
    const int total = NI * (HDIM / 4);
    if (idx >= total) return;
    const int i = idx >> 4;
    const float c = cnt[i];
    const float s = (c > 0.0f) ? __builtin_amdgcn_rcpf(c) : 0.0f;
    float4* o = reinterpret_cast<float4*>(out);
    float4 v = o[idx];
    v.x *= s; v.y *= s; v.z *= s; v.w *= s;
    o[idx] = v;
}

extern "C" void kernel_launch(void* const* d_in, const int* in_sizes, int n_in,
                              void* d_out, int out_size, void* d_ws, size_t ws_size,
                              hipStream_t stream)
{
    const int*   seq  = (const int*)d_in[0];
    const int*   lens = (const int*)d_in[1];
    const float* emb  = (const float*)d_in[2];
    const float* W_ih = (const float*)d_in[3];
    const float* W_hh = (const float*)d_in[4];
    const float* b_ih = (const float*)d_in[5];
    const float* b_hh = (const float*)d_in[6];
    float* out = (float*)d_out;

    const int U  = in_sizes[1];
    const int T  = in_sizes[0] / U;
    const int NI = in_sizes[2] / EDIM;

    // ws layout: cnt[NI] f32 | order[U] i32
    float* cnt   = (float*)d_ws;
    int*   order = (int*)d_ws + NI;

    hipMemsetAsync(out, 0, (size_t)NI * HDIM * sizeof(float), stream);
    hipMemsetAsync(cnt, 0, (size_t)NI * sizeof(float), stream);

    k_sort<<<1, 1024, 0, stream>>>(lens, U, order);

    const int nblk = (U + 63) / 64;   // 64 users per block (4 independent waves x 16)
    lstm_wave<<<nblk, 256, 0, stream>>>(seq, lens, emb, W_ih, W_hh, b_ih, b_hh,
                                        order, out, cnt, U, T);

    const int total = NI * (HDIM / 4);
    finalize_mean<<<(total + 255) / 256, 256, 0, stream>>>(out, cnt, NI);
}